// Round 10
// baseline (190.351 us; speedup 1.0000x reference)
//
#include <hip/hip_runtime.h>

#define N_NODES 100000
#define N_EDGES 1600000
#define D_FEAT 64

#define RB_LOG 6
#define ROWS_PER_BUCKET 64
#define N_BUCKET ((N_NODES + ROWS_PER_BUCKET - 1) / ROWS_PER_BUCKET)  // 1563

#define COL_BITS 17
#define COL_MASK ((1 << COL_BITS) - 1)

// ---- scatter geometry: tile-major rec2, deterministic slots, NO atomics ---
#define NT 256                 // tiles
#define STILE 6250             // 256 * 6250 = 1,600,000 exactly
#define STHREADS 1024
#define SEPT 7                 // ceil(6250/1024)
#define BSTRIDE 1568           // boffT per-tile row stride (>= N_BUCKET+1)

#define CAP_R 1536             // gather recbuf; bucket mean 1024, +16 sigma

__global__ __launch_bounds__(STHREADS) void scatter_kernel(
    const float* __restrict__ vals, const int* __restrict__ rows,
    const int* __restrict__ cols, int2* __restrict__ rec2,
    int* __restrict__ boffT)
{
    __shared__ int hist[N_BUCKET];           // 6.25 KB
    __shared__ int lbase[N_BUCKET + 1];      // 6.25 KB
    __shared__ int ss[2][STHREADS];          // 8 KB scan ping-pong

    int tid = threadIdx.x;
    int bid = blockIdx.x;
    int t0 = bid * STILE;

    for (int i = tid; i < N_BUCKET; i += STHREADS) hist[i] = 0;
    __syncthreads();

    // ---- load edges into registers (coalesced) + rank within tile ----
    int er[SEPT], ec[SEPT], eb[SEPT], rk[SEPT];
    float ev[SEPT];
    #pragma unroll
    for (int j = 0; j < SEPT; ++j) {
        int el = j * STHREADS + tid;
        if (el < STILE) {
            int e = t0 + el;
            er[j] = rows[e]; ec[j] = cols[e]; ev[j] = vals[e];
            eb[j] = er[j] >> RB_LOG;
            rk[j] = atomicAdd(&hist[eb[j]], 1);
        } else {
            eb[j] = -1;
        }
    }
    __syncthreads();

    // ---- exclusive scan hist[0..1562] -> lbase[0..1563] (chunk of 2) ----
    int c0 = (2 * tid     < N_BUCKET) ? hist[2 * tid]     : 0;
    int c1 = (2 * tid + 1 < N_BUCKET) ? hist[2 * tid + 1] : 0;
    ss[0][tid] = c0 + c1;
    __syncthreads();
    int sel = 0;
    for (int off = 1; off < STHREADS; off <<= 1) {
        int x = ss[sel][tid];
        if (tid >= off) x += ss[sel][tid - off];
        ss[1 - sel][tid] = x;
        __syncthreads();
        sel ^= 1;
    }
    int run = tid ? ss[sel][tid - 1] : 0;
    if (2 * tid     <= N_BUCKET) lbase[2 * tid]     = run;
    if (2 * tid + 1 <= N_BUCKET) lbase[2 * tid + 1] = run + c0;
    __syncthreads();

    // ---- publish per-tile offsets, TILE-major (coalesced 6.3 KB burst) ----
    for (int i = tid; i <= N_BUCKET; i += STHREADS)
        boffT[bid * BSTRIDE + i] = lbase[i];

    // ---- direct scattered writes: 8B within the tile's 50 KB rec2 window --
    // (L2 write-combines; no LDS stage / copy-out pass needed)
    #pragma unroll
    for (int j = 0; j < SEPT; ++j) {
        if (eb[j] >= 0) {
            rec2[(size_t)t0 + lbase[eb[j]] + rk[j]] = make_int2(
                ((er[j] & (ROWS_PER_BUCKET - 1)) << COL_BITS) | ec[j],
                __float_as_int(ev[j]));
        }
    }
}

// ---- gather: segment assembly + counting sort + f32 register accumulate ---
#define GTHR 256

__global__ __launch_bounds__(GTHR, 8) void gather_kernel(
    const float* __restrict__ H, const int2* __restrict__ rec2,
    const int* __restrict__ boffT, float* __restrict__ out)
{
    __shared__ int2 recbuf[CAP_R];               // 12 KB, row-sorted
    __shared__ int  rstart[ROWS_PER_BUCKET + 1];
    __shared__ int  rcur[ROWS_PER_BUCKET];
    __shared__ int  sbuf[2][ROWS_PER_BUCKET];
    __shared__ int  tbs[NT], tes[NT];            // segment bounds per tile

    int b = blockIdx.x;
    int tid = threadIdx.x;
    int rg = tid >> 2;       // 0..63 : owns row rg of the bucket
    int f  = tid & 3;        // float4 chunks f, f+4, f+8, f+12
    const float4* H4 = reinterpret_cast<const float4*>(H);

    if (tid < ROWS_PER_BUCKET) rcur[tid] = 0;
    // NT == GTHR: every lane owns one segment (strided boffT reads, L2-hot)
    tbs[tid] = boffT[tid * BSTRIDE + b];
    tes[tid] = boffT[tid * BSTRIDE + b + 1];
    __syncthreads();

    // ---- pass 1: walk segment `tid`, count rows ----
    {
        const int2* seg = rec2 + (size_t)tid * STILE;
        int s = tbs[tid], e = tes[tid];
        for (int i = s; i < e; ++i)
            atomicAdd(&rcur[seg[i].x >> COL_BITS], 1);
    }
    __syncthreads();

    // ---- scan 64 counts -> rstart ----
    if (tid < ROWS_PER_BUCKET) sbuf[0][tid] = rcur[tid];
    __syncthreads();
    int sel = 0;
    for (int off = 1; off < ROWS_PER_BUCKET; off <<= 1) {
        if (tid < ROWS_PER_BUCKET) {
            int x = sbuf[sel][tid];
            if (tid >= off) x += sbuf[sel][tid - off];
            sbuf[1 - sel][tid] = x;
        }
        __syncthreads();
        sel ^= 1;
    }
    if (tid < ROWS_PER_BUCKET) rstart[tid + 1] = sbuf[sel][tid];
    if (tid == 0) rstart[0] = 0;
    __syncthreads();
    if (tid < ROWS_PER_BUCKET) rcur[tid] = rstart[tid];
    __syncthreads();

    // ---- pass 2: re-read segment (L2-hot), place row-sorted ----
    {
        const int2* seg = rec2 + (size_t)tid * STILE;
        int s = tbs[tid], e = tes[tid];
        for (int i = s; i < e; ++i) {
            int2 r = seg[i];
            int pos = atomicAdd(&rcur[r.x >> COL_BITS], 1);
            if (pos < CAP_R) recbuf[pos] = r;
        }
    }
    __syncthreads();

    // ---- register-accumulate for row rg (f32 H, unroll 2) ----
    float4 acc[4];
    #pragma unroll
    for (int q = 0; q < 4; ++q) acc[q] = make_float4(0.f, 0.f, 0.f, 0.f);

    {
        int s = rstart[rg], e2 = rstart[rg + 1];
        if (e2 > CAP_R) e2 = CAP_R;
        int i = s;
        for (; i + 2 <= e2; i += 2) {
            int2 r0 = recbuf[i];
            int2 r1 = recbuf[i + 1];
            int c0b = (r0.x & COL_MASK) * 16;
            int c1b = (r1.x & COL_MASK) * 16;
            float4 h00 = H4[c0b + f],      h01 = H4[c0b + 4 + f];
            float4 h02 = H4[c0b + 8 + f],  h03 = H4[c0b + 12 + f];
            float4 h10 = H4[c1b + f],      h11 = H4[c1b + 4 + f];
            float4 h12 = H4[c1b + 8 + f],  h13 = H4[c1b + 12 + f];
            float v0 = __int_as_float(r0.y);
            float v1 = __int_as_float(r1.y);
            acc[0].x += v0 * h00.x; acc[0].y += v0 * h00.y;
            acc[0].z += v0 * h00.z; acc[0].w += v0 * h00.w;
            acc[1].x += v0 * h01.x; acc[1].y += v0 * h01.y;
            acc[1].z += v0 * h01.z; acc[1].w += v0 * h01.w;
            acc[2].x += v0 * h02.x; acc[2].y += v0 * h02.y;
            acc[2].z += v0 * h02.z; acc[2].w += v0 * h02.w;
            acc[3].x += v0 * h03.x; acc[3].y += v0 * h03.y;
            acc[3].z += v0 * h03.z; acc[3].w += v0 * h03.w;
            acc[0].x += v1 * h10.x; acc[0].y += v1 * h10.y;
            acc[0].z += v1 * h10.z; acc[0].w += v1 * h10.w;
            acc[1].x += v1 * h11.x; acc[1].y += v1 * h11.y;
            acc[1].z += v1 * h11.z; acc[1].w += v1 * h11.w;
            acc[2].x += v1 * h12.x; acc[2].y += v1 * h12.y;
            acc[2].z += v1 * h12.z; acc[2].w += v1 * h12.w;
            acc[3].x += v1 * h13.x; acc[3].y += v1 * h13.y;
            acc[3].z += v1 * h13.z; acc[3].w += v1 * h13.w;
        }
        for (; i < e2; ++i) {
            int2 r0 = recbuf[i];
            int c0b = (r0.x & COL_MASK) * 16;
            float4 h00 = H4[c0b + f],     h01 = H4[c0b + 4 + f];
            float4 h02 = H4[c0b + 8 + f], h03 = H4[c0b + 12 + f];
            float v0 = __int_as_float(r0.y);
            acc[0].x += v0 * h00.x; acc[0].y += v0 * h00.y;
            acc[0].z += v0 * h00.z; acc[0].w += v0 * h00.w;
            acc[1].x += v0 * h01.x; acc[1].y += v0 * h01.y;
            acc[1].z += v0 * h01.z; acc[1].w += v0 * h01.w;
            acc[2].x += v0 * h02.x; acc[2].y += v0 * h02.y;
            acc[2].z += v0 * h02.z; acc[2].w += v0 * h02.w;
            acc[3].x += v0 * h03.x; acc[3].y += v0 * h03.y;
            acc[3].z += v0 * h03.z; acc[3].w += v0 * h03.w;
        }
    }

    // ---- coalesced writeback, exactly once ----
    int row = b * ROWS_PER_BUCKET + rg;
    if (row < N_NODES) {
        float4* o4 = reinterpret_cast<float4*>(out);
        o4[row * 16 + f]      = acc[0];
        o4[row * 16 + 4 + f]  = acc[1];
        o4[row * 16 + 8 + f]  = acc[2];
        o4[row * 16 + 12 + f] = acc[3];
    }
}

extern "C" void kernel_launch(void* const* d_in, const int* in_sizes, int n_in,
                              void* d_out, int out_size, void* d_ws, size_t ws_size,
                              hipStream_t stream) {
    const float* H    = (const float*)d_in[0];
    const float* vals = (const float*)d_in[1];
    const int*   rows = (const int*)d_in[2];
    const int*   cols = (const int*)d_in[3];
    float* out = (float*)d_out;

    int2* rec2  = (int2*)d_ws;                          // 256*6250*8B = 12.8 MB
    int*  boffT = (int*)(rec2 + (size_t)NT * STILE);    // 256*1568*4B = 1.6 MB

    // no memset: boffT fully rewritten each run; rec2 read only within
    // [tb,te) ranges written this run.
    scatter_kernel<<<NT, STHREADS, 0, stream>>>(vals, rows, cols, rec2, boffT);
    gather_kernel<<<N_BUCKET, GTHR, 0, stream>>>(H, rec2, boffT, out);
}

// Round 11
// 156.978 us; speedup vs baseline: 1.2126x; 1.2126x over previous
//
#include <hip/hip_runtime.h>

#define N_NODES 100000
#define N_EDGES 1600000
#define D_FEAT 64

#define RB_LOG 6
#define ROWS_PER_BUCKET 64
#define N_BUCKET ((N_NODES + ROWS_PER_BUCKET - 1) / ROWS_PER_BUCKET)  // 1563

#define COL_BITS 17
#define COL_MASK ((1 << COL_BITS) - 1)

// ---- scatter geometry (r8-proven): fat tiles, staged burst write ----------
#define STILE 8192
#define STHREADS 1024
#define SEPT (STILE / STHREADS)               // 8
#define NT ((N_EDGES + STILE - 1) / STILE)    // 196 tiles
#define NTCOL 256                             // boffT bucket-row stride

#define CAP_R 1536     // bucket records; mean 1024, sigma ~32 -> +16 sigma

__global__ __launch_bounds__(STHREADS) void scatter_kernel(
    const float* __restrict__ vals, const int* __restrict__ rows,
    const int* __restrict__ cols, int2* __restrict__ rec2,
    int* __restrict__ boffT)
{
    __shared__ int2 stage[STILE];             // 64 KB (head reused as scan buf)
    __shared__ int  hist[N_BUCKET];           // 6.25 KB
    __shared__ int  lbase[N_BUCKET + 1];      // 6.25 KB

    int tid = threadIdx.x;
    int tile = blockIdx.x;
    int t0 = tile * STILE;

    for (int i = tid; i < N_BUCKET; i += STHREADS) hist[i] = 0;
    __syncthreads();

    // ---- load edges into registers (coalesced) + rank within tile ----
    int er[SEPT], ec[SEPT], eb[SEPT], rk[SEPT];
    float ev[SEPT];
    #pragma unroll
    for (int j = 0; j < SEPT; ++j) {
        int e = t0 + j * STHREADS + tid;
        if (e < N_EDGES) {
            er[j] = rows[e]; ec[j] = cols[e]; ev[j] = vals[e];
            eb[j] = er[j] >> RB_LOG;
            rk[j] = atomicAdd(&hist[eb[j]], 1);
        } else {
            eb[j] = -1;
        }
    }
    __syncthreads();

    // ---- exclusive scan hist -> lbase (chunk of 2; ping-pong in stage) ----
    int* ss = (int*)stage;
    int c0 = (2 * tid     < N_BUCKET) ? hist[2 * tid]     : 0;
    int c1 = (2 * tid + 1 < N_BUCKET) ? hist[2 * tid + 1] : 0;
    ss[tid] = c0 + c1;
    __syncthreads();
    int sel = 0;
    for (int off = 1; off < STHREADS; off <<= 1) {
        int x = ss[sel * STHREADS + tid];
        if (tid >= off) x += ss[sel * STHREADS + tid - off];
        ss[(1 - sel) * STHREADS + tid] = x;
        __syncthreads();
        sel ^= 1;
    }
    int run = tid ? ss[sel * STHREADS + tid - 1] : 0;
    if (2 * tid     <= N_BUCKET) lbase[2 * tid]     = run;
    if (2 * tid + 1 <= N_BUCKET) lbase[2 * tid + 1] = run + c0;
    __syncthreads();   // scan buffer dead; stage reusable

    // ---- publish per-tile offsets, BUCKET-major (gather reads coalesced) --
    for (int i = tid; i <= N_BUCKET; i += STHREADS)
        boffT[i * NTCOL + tile] = lbase[i];

    // ---- place records bucket-sorted into LDS stage ----
    #pragma unroll
    for (int j = 0; j < SEPT; ++j) {
        if (eb[j] >= 0) {
            stage[lbase[eb[j]] + rk[j]] = make_int2(
                ((er[j] & (ROWS_PER_BUCKET - 1)) << COL_BITS) | ec[j],
                __float_as_int(ev[j]));
        }
    }
    __syncthreads();

    // ---- linear coalesced copy-out ----
    int ntot = lbase[N_BUCKET];
    const int4* s4 = reinterpret_cast<const int4*>(stage);
    int4* d4 = reinterpret_cast<int4*>(rec2 + (size_t)t0);
    for (int i = tid; i < (ntot >> 1); i += STHREADS) d4[i] = s4[i];
    if ((ntot & 1) && tid == 0) rec2[(size_t)t0 + ntot - 1] = stage[ntot - 1];
}

// ---- gather: single-walk stage+count, LDS order-sort, f32 accumulate ------
#define GTHR 256

__global__ __launch_bounds__(GTHR, 8) void gather_kernel(
    const float* __restrict__ H, const int2* __restrict__ rec2,
    const int* __restrict__ boffT, float* __restrict__ out)
{
    __shared__ int2           raw[CAP_R];        // 12 KB, arrival order
    __shared__ unsigned short order[CAP_R];      // 3 KB, row-sorted indices
    __shared__ int            sbuf[2][GTHR];     // 2 KB scan ping-pong
    __shared__ int            rstart[ROWS_PER_BUCKET + 1];
    __shared__ int            rcur[ROWS_PER_BUCKET];

    // bijective XCD swizzle (1563 = 8*195 + 3): chunk consecutive buckets
    // onto one XCD so segment-boundary rec2 lines are L2-shared.
    int orig = blockIdx.x;
    int xcd = orig & 7, idx = orig >> 3;
    const int q = N_BUCKET >> 3, r = N_BUCKET & 7;        // 195, 3
    int b = (xcd < r) ? xcd * (q + 1) + idx
                      : r * (q + 1) + (xcd - r) * q + idx;

    int tid = threadIdx.x;
    int rg = tid >> 2;       // 0..63 : owns row rg of the bucket
    int f  = tid & 3;        // float4 chunks f, f+4, f+8, f+12
    const float4* H4 = reinterpret_cast<const float4*>(H);

    // ---- segment bounds (bucket-major boffT: coalesced) + zero counters ---
    int tb = 0, len = 0;
    if (tid < NT) {
        tb = boffT[b * NTCOL + tid];
        len = boffT[(b + 1) * NTCOL + tid] - tb;
    }
    if (tid < ROWS_PER_BUCKET) rcur[tid] = 0;

    // ---- scan 256 segment lengths -> packed bases ----
    sbuf[0][tid] = len;
    __syncthreads();
    int sel = 0;
    for (int off = 1; off < GTHR; off <<= 1) {
        int x = sbuf[sel][tid];
        if (tid >= off) x += sbuf[sel][tid - off];
        sbuf[1 - sel][tid] = x;
        __syncthreads();
        sel ^= 1;
    }
    int sbase = sbuf[sel][tid] - len;          // exclusive
    int n = sbuf[sel][GTHR - 1];               // total records this bucket
    if (n > CAP_R) n = CAP_R;
    __syncthreads();

    // ---- single global walk: stage packed into LDS + count rows ----
    {
        const int2* seg = rec2 + (size_t)tid * STILE;
        for (int k = 0; k < len; ++k) {
            int2 rr = seg[tb + k];
            int p = sbase + k;
            if (p < CAP_R) raw[p] = rr;
            atomicAdd(&rcur[rr.x >> COL_BITS], 1);
        }
    }
    __syncthreads();

    // ---- scan 64 row counts -> rstart ----
    if (tid < ROWS_PER_BUCKET) sbuf[0][tid] = rcur[tid];
    __syncthreads();
    sel = 0;
    for (int off = 1; off < ROWS_PER_BUCKET; off <<= 1) {
        if (tid < ROWS_PER_BUCKET) {
            int x = sbuf[sel][tid];
            if (tid >= off) x += sbuf[sel][tid - off];
            sbuf[1 - sel][tid] = x;
        }
        __syncthreads();
        sel ^= 1;
    }
    if (tid < ROWS_PER_BUCKET) rstart[tid + 1] = sbuf[sel][tid];
    if (tid == 0) rstart[0] = 0;
    __syncthreads();
    if (tid < ROWS_PER_BUCKET) rcur[tid] = rstart[tid];
    __syncthreads();

    // ---- LDS->LDS order-sort (coalesced stride-256 over raw) ----
    for (int i = tid; i < n; i += GTHR) {
        int ro = raw[i].x >> COL_BITS;
        int pos = atomicAdd(&rcur[ro], 1);
        order[pos] = (unsigned short)i;
    }
    __syncthreads();

    // ---- register-accumulate for row rg (f32 H, unroll 2) ----
    float4 acc[4];
    #pragma unroll
    for (int qq = 0; qq < 4; ++qq) acc[qq] = make_float4(0.f, 0.f, 0.f, 0.f);

    {
        int s = rstart[rg], e2 = rstart[rg + 1];
        if (e2 > n) e2 = n;
        int i = s;
        for (; i + 2 <= e2; i += 2) {
            int2 r0 = raw[order[i]];
            int2 r1 = raw[order[i + 1]];
            int c0b = (r0.x & COL_MASK) * 16;
            int c1b = (r1.x & COL_MASK) * 16;
            float4 h00 = H4[c0b + f],      h01 = H4[c0b + 4 + f];
            float4 h02 = H4[c0b + 8 + f],  h03 = H4[c0b + 12 + f];
            float4 h10 = H4[c1b + f],      h11 = H4[c1b + 4 + f];
            float4 h12 = H4[c1b + 8 + f],  h13 = H4[c1b + 12 + f];
            float v0 = __int_as_float(r0.y);
            float v1 = __int_as_float(r1.y);
            acc[0].x += v0 * h00.x; acc[0].y += v0 * h00.y;
            acc[0].z += v0 * h00.z; acc[0].w += v0 * h00.w;
            acc[1].x += v0 * h01.x; acc[1].y += v0 * h01.y;
            acc[1].z += v0 * h01.z; acc[1].w += v0 * h01.w;
            acc[2].x += v0 * h02.x; acc[2].y += v0 * h02.y;
            acc[2].z += v0 * h02.z; acc[2].w += v0 * h02.w;
            acc[3].x += v0 * h03.x; acc[3].y += v0 * h03.y;
            acc[3].z += v0 * h03.z; acc[3].w += v0 * h03.w;
            acc[0].x += v1 * h10.x; acc[0].y += v1 * h10.y;
            acc[0].z += v1 * h10.z; acc[0].w += v1 * h10.w;
            acc[1].x += v1 * h11.x; acc[1].y += v1 * h11.y;
            acc[1].z += v1 * h11.z; acc[1].w += v1 * h11.w;
            acc[2].x += v1 * h12.x; acc[2].y += v1 * h12.y;
            acc[2].z += v1 * h12.z; acc[2].w += v1 * h12.w;
            acc[3].x += v1 * h13.x; acc[3].y += v1 * h13.y;
            acc[3].z += v1 * h13.z; acc[3].w += v1 * h13.w;
        }
        for (; i < e2; ++i) {
            int2 r0 = raw[order[i]];
            int c0b = (r0.x & COL_MASK) * 16;
            float4 h00 = H4[c0b + f],     h01 = H4[c0b + 4 + f];
            float4 h02 = H4[c0b + 8 + f], h03 = H4[c0b + 12 + f];
            float v0 = __int_as_float(r0.y);
            acc[0].x += v0 * h00.x; acc[0].y += v0 * h00.y;
            acc[0].z += v0 * h00.z; acc[0].w += v0 * h00.w;
            acc[1].x += v0 * h01.x; acc[1].y += v0 * h01.y;
            acc[1].z += v0 * h01.z; acc[1].w += v0 * h01.w;
            acc[2].x += v0 * h02.x; acc[2].y += v0 * h02.y;
            acc[2].z += v0 * h02.z; acc[2].w += v0 * h02.w;
            acc[3].x += v0 * h03.x; acc[3].y += v0 * h03.y;
            acc[3].z += v0 * h03.z; acc[3].w += v0 * h03.w;
        }
    }

    // ---- coalesced writeback, exactly once ----
    int row = b * ROWS_PER_BUCKET + rg;
    if (row < N_NODES) {
        float4* o4 = reinterpret_cast<float4*>(out);
        o4[row * 16 + f]      = acc[0];
        o4[row * 16 + 4 + f]  = acc[1];
        o4[row * 16 + 8 + f]  = acc[2];
        o4[row * 16 + 12 + f] = acc[3];
    }
}

extern "C" void kernel_launch(void* const* d_in, const int* in_sizes, int n_in,
                              void* d_out, int out_size, void* d_ws, size_t ws_size,
                              hipStream_t stream) {
    const float* H    = (const float*)d_in[0];
    const float* vals = (const float*)d_in[1];
    const int*   rows = (const int*)d_in[2];
    const int*   cols = (const int*)d_in[3];
    float* out = (float*)d_out;

    int2* rec2  = (int2*)d_ws;                          // 196*8192*8B = 12.85 MB
    int*  boffT = (int*)(rec2 + (size_t)NT * STILE);    // 1564*256*4B = 1.6 MB

    // no memset: boffT fully rewritten each run; rec2 read only within
    // [tb,te) ranges written this run.
    scatter_kernel<<<NT, STHREADS, 0, stream>>>(vals, rows, cols, rec2, boffT);
    gather_kernel<<<N_BUCKET, GTHR, 0, stream>>>(H, rec2, boffT, out);
}